// Round 15
// baseline (318.304 us; speedup 1.0000x reference)
//
#include <hip/hip_runtime.h>
#include <hip/hip_bf16.h>
#include <math.h>

#define NB 2
#define NS 2048
#define ND 1024
#define NH 16
#define NHD 64
#define NDFF 4096

typedef __attribute__((ext_vector_type(4))) float f32x4;
typedef __attribute__((ext_vector_type(8))) short bf16x8;

__device__ __forceinline__ short f2bf(float f) {
  union { float f; unsigned u; } v; v.f = f;
  unsigned r = v.u + 0x7fffu + ((v.u >> 16) & 1u);
  return (short)(r >> 16);
}
__device__ __forceinline__ float bf2f(unsigned short u) {
  union { unsigned u; float f; } v; v.u = ((unsigned)u) << 16; return v.f;
}
__device__ __forceinline__ float softplus_f(float x) {
  return fmaxf(x, 0.f) + log1pf(__expf(-fabsf(x)));
}
// async global->LDS, 16B per lane; LDS dest wave-uniform (HW adds lane*16)
__device__ __forceinline__ void gl16(const short* g, short* l) {
  __builtin_amdgcn_global_load_lds(
      (const __attribute__((address_space(1))) void*)g,
      (__attribute__((address_space(3))) void*)l, 16, 0, 0);
}
// XCD-chunked bijective block remap (T1), 128-row x 256-col tiles.
__device__ __forceinline__ void xcd_map256(int& row0, int& col0) {
  const int gx = gridDim.x, gy = gridDim.y;
  const int bid = blockIdx.y * gx + blockIdx.x;
  const int rows_px = gy >> 3;
  const int xcd = bid & 7, l = bid >> 3;
  row0 = (xcd * rows_px + (l % rows_px)) * 128;
  col0 = (l / rows_px) * 256;
}

// ============ prep: all 6 weight transposes + x->bf16 in ONE dispatch ============
__global__ __launch_bounds__(256) void k_prep(
    const float* __restrict__ wq, const float* __restrict__ wk,
    const float* __restrict__ wv, const float* __restrict__ wo,
    const float* __restrict__ w1, const float* __restrict__ w2,
    const float* __restrict__ x,
    short* __restrict__ wqT, short* __restrict__ wkT, short* __restrict__ wvT,
    short* __restrict__ woT, short* __restrict__ w1T, short* __restrict__ w2T,
    short* __restrict__ xb) {
  __shared__ float t[64][65];
  const int bid = blockIdx.x;
  if (bid >= 3072) {
    const int i = (bid - 3072) * 256 + threadIdx.x;
    const float4 a = ((const float4*)x)[i * 2];
    const float4 b = ((const float4*)x)[i * 2 + 1];
    short tmp[8] = { f2bf(a.x), f2bf(a.y), f2bf(a.z), f2bf(a.w),
                     f2bf(b.x), f2bf(b.y), f2bf(b.z), f2bf(b.w) };
    *(int4*)&xb[(size_t)i * 8] = *(const int4*)tmp;
    return;
  }
  const float* W; short* Wt; int K, N, local;
  if (bid < 1024) {
    const int wsel = bid >> 8; local = bid & 255;
    W  = wsel == 0 ? wq  : wsel == 1 ? wk  : wsel == 2 ? wv  : wo;
    Wt = wsel == 0 ? wqT : wsel == 1 ? wkT : wsel == 2 ? wvT : woT;
    K = ND; N = ND;
  } else if (bid < 2048) {
    local = bid - 1024; W = w1; Wt = w1T; K = ND; N = NDFF;
  } else {
    local = bid - 2048; W = w2; Wt = w2T; K = NDFF; N = ND;
  }
  const int nx = N >> 6;
  const int n0 = (local % nx) * 64, k0 = (local / nx) * 64;
  for (int i = threadIdx.x; i < 4096; i += 256) {
    const int r = i >> 6, c = i & 63;
    t[r][c] = W[(size_t)(k0 + r) * N + n0 + c];
  }
  __syncthreads();
  for (int i = threadIdx.x; i < 4096; i += 256) {
    const int r = i >> 6, c = i & 63;
    Wt[(size_t)(n0 + r) * K + k0 + c] = f2bf(t[c][r]);
  }
}

// ============ PoPE + V-transpose in ONE dispatch ============
__global__ __launch_bounds__(256) void k_pope_pv(const short* __restrict__ qb,
    const short* __restrict__ kb, const short* __restrict__ vb,
    const int* __restrict__ positions, const float* __restrict__ phb,
    short* __restrict__ qp, short* __restrict__ kp, short* __restrict__ vt) {
  __shared__ short t[64][72];
  const int bid = blockIdx.x;
  if (bid < 2048) {
    const size_t i8 = ((size_t)bid * 256 + threadIdx.x) * 8;
    const int d0 = (int)(i8 & 63);
    const int h  = (int)((i8 >> 6) & 15);
    const int s  = (int)((i8 >> 10) & 2047);
    const int b  = (int)(i8 >> 21);
    const float posf = (float)positions[s];
    const float QSC = 0.12751743305610407f;  // 1/sqrt(128) * log2(e)
    int4 qv = *(const int4*)&qb[i8];
    int4 kv = *(const int4*)&kb[i8];
    const short* qs = (const short*)&qv;
    const short* ks = (const short*)&kv;
    short qc[8], qsn[8], kc[8], ksn[8];
#pragma unroll
    for (int j = 0; j < 8; j++) {
      const int d = d0 + j;
      const float freq = __expf(-(float)d * (float)(9.210340371976184 / 64.0));
      const float muq = softplus_f(bf2f((unsigned short)qs[j])) * QSC;
      const float muk = softplus_f(bf2f((unsigned short)ks[j]));
      float cb = phb[h * 64 + d];
      cb = fminf(fmaxf(cb, -6.283185307179586f), 0.f);
      float snq, csq, snk, csk;
      __sincosf(posf * freq, &snq, &csq);
      __sincosf(posf * freq + cb, &snk, &csk);
      qc[j] = f2bf(muq * csq); qsn[j] = f2bf(muq * snq);
      kc[j] = f2bf(muk * csk); ksn[j] = f2bf(muk * snk);
    }
    const size_t o = (((size_t)(b * 16 + h) * NS + s) * 128) + d0;
    *(int4*)&qp[o] = *(const int4*)qc;
    *(int4*)&qp[o + 64] = *(const int4*)qsn;
    *(int4*)&kp[o] = *(const int4*)kc;
    *(int4*)&kp[o + 64] = *(const int4*)ksn;
  } else {
    const int local = bid - 2048;
    const int bh = local >> 5, b = bh >> 4, h = bh & 15;
    const int s0 = (local & 31) * 64;
    for (int i = threadIdx.x; i < 512; i += 256) {
      const int sl = i >> 3, d8 = (i & 7) * 8;
      int4 vv = *(const int4*)&vb[((size_t)(b * NS + s0 + sl) * NH + h) * NHD + d8];
      const short* sp = (const short*)&vv;
#pragma unroll
      for (int j = 0; j < 8; j++) t[d8 + j][sl] = sp[j];
    }
    __syncthreads();
    for (int i = threadIdx.x; i < 512; i += 256) {
      const int d = i >> 3, c8 = (i & 7) * 8;
      *(int4*)&vt[((size_t)bh * 64 + d) * NS + s0 + c8] = *(const int4*)&t[d][c8];
    }
  }
}

// ==== GEMM core 128x256: 2-phase dbuf, global_load_lds, 32 MFMA/barrier/wave ====
#define BKK 32

__device__ __forceinline__ void gemm_core2(const short* __restrict__ A,
    const short* __restrict__ Wt, const int K, const int kbeg, const int kend,
    const int row0, const int col0, short* lsA, short* lsB, f32x4 acc[4][8]) {
  const int tid = threadIdx.x;
  const int lane = tid & 63, wave = tid >> 6;
  const int lr = lane & 15, lk8 = (lane >> 4) << 3;
  const int wr = wave >> 1, wc = wave & 1;          // 2x2 waves of 64x128
  const int srow = lane >> 2, scol = (lane & 3) << 3;
#pragma unroll
  for (int m = 0; m < 4; m++)
#pragma unroll
    for (int n = 0; n < 8; n++) acc[m][n] = 0.f;
  const short* gA0 = &A[(size_t)(row0 + wave * 32 + srow) * K + scol];
  const short* gA1 = gA0 + (size_t)16 * K;
  const short* gB0 = &Wt[(size_t)(col0 + wave * 64 + srow) * K + scol];
  const short* gB1 = gB0 + (size_t)16 * K;
  const short* gB2 = gB0 + (size_t)32 * K;
  const short* gB3 = gB0 + (size_t)48 * K;
  short* const lA0 = lsA + wave * 1024;   // 32 rows * 32 shorts
  short* const lB0 = lsB + wave * 2048;   // 64 rows * 32 shorts
  auto stage = [&](int buf, int kk) {
    const int oA = buf * 4096, oB = buf * 8192;
    gl16(gA0 + kk, lA0 + oA);
    gl16(gA1 + kk, lA0 + oA + 512);
    gl16(gB0 + kk, lB0 + oB);
    gl16(gB1 + kk, lB0 + oB + 512);
    gl16(gB2 + kk, lB0 + oB + 1024);
    gl16(gB3 + kk, lB0 + oB + 1536);
  };
  stage(0, kbeg);
  __syncthreads();
  int cur = 0;
  for (int k0 = kbeg; k0 < kend; k0 += BKK) {
    if (k0 + BKK < kend) stage(cur ^ 1, k0 + BKK);  // issue-early
    const short* la = lsA + cur * 4096;
    const short* lb = lsB + cur * 8192;
    bf16x8 af[4], bf_[8];
#pragma unroll
    for (int m = 0; m < 4; m++)
      af[m] = *(const bf16x8*)&la[(wr * 64 + m * 16 + lr) * 32 + lk8];
#pragma unroll
    for (int n = 0; n < 8; n++)
      bf_[n] = *(const bf16x8*)&lb[(wc * 128 + n * 16 + lr) * 32 + lk8];
#pragma unroll
    for (int m = 0; m < 4; m++)
#pragma unroll
      for (int n = 0; n < 8; n++)
        acc[m][n] = __builtin_amdgcn_mfma_f32_16x16x32_bf16(af[m], bf_[n], acc[m][n], 0, 0, 0);
    __syncthreads();
    cur ^= 1;
  }
}

template<int RELU, int OUTBF16>
__global__ __launch_bounds__(256) void k_gemm(const short* __restrict__ A,
    const short* __restrict__ Wt, const float* __restrict__ bias,
    void* __restrict__ C, int M, int N, int K) {
  __shared__ short lsA[2 * 4096], lsB[2 * 8192];
  f32x4 acc[4][8];
  int row0, col0;
  xcd_map256(row0, col0);
  gemm_core2(A, Wt, K, 0, K, row0, col0, lsA, lsB, acc);
  const int lane = threadIdx.x & 63, wave = threadIdx.x >> 6;
  const int lr = lane & 15, r4 = (lane >> 4) << 2;
  const int wr = wave >> 1, wc = wave & 1;
#pragma unroll
  for (int m = 0; m < 4; m++) {
#pragma unroll
    for (int n = 0; n < 8; n++) {
      const int col = col0 + wc * 128 + n * 16 + lr;
      const float bv = bias[col];
#pragma unroll
      for (int r = 0; r < 4; r++) {
        const int row = row0 + wr * 64 + m * 16 + r4 + r;
        float val = acc[m][n][r] + bv;
        if (RELU) val = fmaxf(val, 0.f);
        if (OUTBF16) ((short*)C)[(size_t)row * N + col] = f2bf(val);
        else ((float*)C)[(size_t)row * N + col] = val;
      }
    }
  }
}

// QKV merged: grid.z picks weight/bias/output. bf16 out.
__global__ __launch_bounds__(256) void k_gemm3(const short* __restrict__ xb,
    const short* __restrict__ wqT, const short* __restrict__ wkT,
    const short* __restrict__ wvT, const float* __restrict__ bq,
    const float* __restrict__ bk, const float* __restrict__ bv,
    short* __restrict__ qb, short* __restrict__ kb, short* __restrict__ vb) {
  __shared__ short lsA[2 * 4096], lsB[2 * 8192];
  const int z = blockIdx.z;
  const short* Wt = (z == 0) ? wqT : (z == 1) ? wkT : wvT;
  const float* bias = (z == 0) ? bq : (z == 1) ? bk : bv;
  short* C = (z == 0) ? qb : (z == 1) ? kb : vb;
  f32x4 acc[4][8];
  int row0, col0;
  xcd_map256(row0, col0);
  gemm_core2(xb, Wt, ND, 0, ND, row0, col0, lsA, lsB, acc);
  const int lane = threadIdx.x & 63, wave = threadIdx.x >> 6;
  const int lr = lane & 15, r4 = (lane >> 4) << 2;
  const int wr = wave >> 1, wc = wave & 1;
#pragma unroll
  for (int m = 0; m < 4; m++) {
#pragma unroll
    for (int n = 0; n < 8; n++) {
      const int col = col0 + wc * 128 + n * 16 + lr;
      const float bvs = bias[col];
#pragma unroll
      for (int r = 0; r < 4; r++) {
        const int row = row0 + wr * 64 + m * 16 + r4 + r;
        C[(size_t)row * ND + col] = f2bf(acc[m][n][r] + bvs);
      }
    }
  }
}

// Split-K GEMM: grid.z=2 halves of K; writes unbiased f32 partials to C0/C1.
__global__ __launch_bounds__(256) void k_gemm_sk(const short* __restrict__ A,
    const short* __restrict__ Wt, float* __restrict__ C0, float* __restrict__ C1,
    int M, int N, int K) {
  __shared__ short lsA[2 * 4096], lsB[2 * 8192];
  f32x4 acc[4][8];
  const int z = blockIdx.z;
  const int khalf = K >> 1, kbeg = z * khalf, kend = kbeg + khalf;
  int row0, col0;
  xcd_map256(row0, col0);
  gemm_core2(A, Wt, K, kbeg, kend, row0, col0, lsA, lsB, acc);
  float* C = z ? C1 : C0;
  const int lane = threadIdx.x & 63, wave = threadIdx.x >> 6;
  const int lr = lane & 15, r4 = (lane >> 4) << 2;
  const int wr = wave >> 1, wc = wave & 1;
#pragma unroll
  for (int m = 0; m < 4; m++) {
#pragma unroll
    for (int n = 0; n < 8; n++) {
      const int col = col0 + wc * 128 + n * 16 + lr;
#pragma unroll
      for (int r = 0; r < 4; r++) {
        const int row = row0 + wr * 64 + m * 16 + r4 + r;
        C[(size_t)row * N + col] = acc[m][n][r];
      }
    }
  }
}

// ============ Attention (causal, softmax1), MFMA flash (r11-proven) ============
__device__ __forceinline__ void attn_proc(const bf16x8 aq[4], f32x4 acc_o[4],
    float l_p[4], const int rowb, const int kb,
    const short (*kpl)[136], const short (*vl)[72], short (*pl)[72],
    const int lr, const int lk) {
  f32x4 s_acc[4];
#pragma unroll
  for (int n = 0; n < 4; n++) s_acc[n] = 0.f;
#pragma unroll
  for (int ks = 0; ks < 4; ks++) {
    bf16x8 bk_[4];
#pragma unroll
    for (int n = 0; n < 4; n++)
      bk_[n] = *(const bf16x8*)&kpl[n * 16 + lr][ks * 32 + lk * 8];
#pragma unroll
    for (int n = 0; n < 4; n++)
      s_acc[n] = __builtin_amdgcn_mfma_f32_16x16x32_bf16(aq[ks], bk_[n], s_acc[n], 0, 0, 0);
  }
  const bool domask = (kb + 63 > rowb);  // wave-uniform: diagonal-crossing chunk
#pragma unroll
  for (int n = 0; n < 4; n++) {
#pragma unroll
    for (int r = 0; r < 4; r++) {
      float p = __builtin_amdgcn_exp2f(s_acc[n][r]);  // raw v_exp_f32
      if (domask) {
        const int rel = rowb + lk * 4 + r - kb;
        p = (n * 16 + lr <= rel) ? p : 0.f;
      }
      unsigned pu = __float_as_uint(p) & 0xFFFF0000u;  // truncate to bf16
      l_p[r] += __uint_as_float(pu);
      pl[lk * 4 + r][n * 16 + lr] = (short)(pu >> 16);
    }
  }
#pragma unroll
  for (int ks = 0; ks < 2; ks++) {
    const bf16x8 ap = *(const bf16x8*)&pl[lr][ks * 32 + lk * 8];
    bf16x8 bv_[4];
#pragma unroll
    for (int nd = 0; nd < 4; nd++)
      bv_[nd] = *(const bf16x8*)&vl[nd * 16 + lr][ks * 32 + lk * 8];
#pragma unroll
    for (int nd = 0; nd < 4; nd++)
      acc_o[nd] = __builtin_amdgcn_mfma_f32_16x16x32_bf16(ap, bv_[nd], acc_o[nd], 0, 0, 0);
  }
}

// grid (16, 32), 512 threads, 2 blocks/CU. XCD-grouped heads.
__global__ __launch_bounds__(512) void k_attn3(
    const short* __restrict__ qp, const short* __restrict__ kp,
    const short* __restrict__ vt, short* __restrict__ attn) {
  __shared__ short kp_l[2][64][136];
  __shared__ short v_l[2][64][72];
  __shared__ short p_l[8][16][72];
  const int bid = blockIdx.y * gridDim.x + blockIdx.x;
  const int xcd = bid & 7, o = bid >> 3;
  const int bh = xcd * 4 + (o >> 4);
  const int bx = o & 15;
  const int b = bh >> 4, h = bh & 15;
  const int tid = threadIdx.x, wave = tid >> 6, lane = tid & 63;
  const int lr = lane & 15, lk = lane >> 4;
  const int tHeavy = 31 - bx;
  const int myTile = (wave < 4) ? tHeavy : bx;
  const int rowb = myTile * 64 + (wave & 3) * 16;
  const int nch = tHeavy + 1;

  bf16x8 aq[4];
  {
    const short* qrow = qp + ((size_t)bh * NS + rowb + lr) * 128;
#pragma unroll
    for (int ks = 0; ks < 4; ks++)
      aq[ks] = *(const bf16x8*)&qrow[ks * 32 + lk * 8];
  }
  f32x4 acc[4];
  float lsum[4];
#pragma unroll
  for (int r = 0; r < 4; r++) lsum[r] = 0.f;
#pragma unroll
  for (int n = 0; n < 4; n++) acc[n] = 0.f;

  const short* kpb = kp + (size_t)bh * NS * 128;
  const short* vtb = vt + (size_t)bh * 64 * NS;
  const int krow = tid >> 3, kcol = (tid & 7) * 16;
  const int vrow = tid >> 3, vcol = (tid & 7) * 8;

  int4 rk0, rk1, rv;
  {
    const short* s = &kpb[(size_t)krow * 128 + kcol];
    rk0 = ((const int4*)s)[0]; rk1 = ((const int4*)s)[1];
    rv = *(const int4*)&vtb[(size_t)vrow * NS + vcol];
  }
  ((int4*)&kp_l[0][krow][kcol])[0] = rk0;
  ((int4*)&kp_l[0][krow][kcol])[1] = rk1;
  *(int4*)&v_l[0][vrow][vcol] = rv;
  __syncthreads();

  for (int c = 0; c < nch; c++) {
    const int kb = c * 64;
    const int cur = c & 1;
    const bool more = (c + 1) < nch;
    if (more) {
      const int kb2 = kb + 64;
      const short* s = &kpb[(size_t)(kb2 + krow) * 128 + kcol];
      rk0 = ((const int4*)s)[0]; rk1 = ((const int4*)s)[1];
      rv = *(const int4*)&vtb[(size_t)vrow * NS + kb2 + vcol];
    }
    if (rowb + 15 >= kb)
      attn_proc(aq, acc, lsum, rowb, kb, kp_l[cur], v_l[cur], p_l[wave], lr, lk);
    if (more) {
      ((int4*)&kp_l[cur ^ 1][krow][kcol])[0] = rk0;
      ((int4*)&kp_l[cur ^ 1][krow][kcol])[1] = rk1;
      *(int4*)&v_l[cur ^ 1][vrow][vcol] = rv;
    }
    __syncthreads();
  }
#pragma unroll
  for (int r = 0; r < 4; r++) {
    float s = lsum[r];
#pragma unroll
    for (int off = 8; off; off >>= 1) s += __shfl_xor(s, off);
    lsum[r] = 1.f / (1.f + s);   // softmax1 with m=0: denom = 1 + sum
  }
#pragma unroll
  for (int nd = 0; nd < 4; nd++) {
#pragma unroll
    for (int r = 0; r < 4; r++) {
      const int d = nd * 16 + lr;
      const int row = rowb + lk * 4 + r;
      attn[(((size_t)b * NS + row) * NH + h) * NHD + d] = f2bf(acc[nd][r] * lsum[r]);
    }
  }
}

// ==== LayerNorm with fused partial-sum + bias: x = A0 + A1 + badd + R ====
template<int RBF16, int OUTBF16>
__global__ __launch_bounds__(256) void k_ln3(const float* __restrict__ A0,
    const float* __restrict__ A1, const float* __restrict__ badd,
    const void* __restrict__ Rv, const float* __restrict__ g,
    const float* __restrict__ be, void* __restrict__ out) {
  const int row = blockIdx.x, tid = threadIdx.x;
  const float4 a0 = ((const float4*)(A0 + (size_t)row * ND))[tid];
  const float4 a1 = ((const float4*)(A1 + (size_t)row * ND))[tid];
  const float4 bd = ((const float4*)badd)[tid];
  float r0, r1, r2, r3;
  if (RBF16) {
    short4 rr = *(const short4*)((const short*)Rv + (size_t)row * ND + tid * 4);
    r0 = bf2f((unsigned short)rr.x); r1 = bf2f((unsigned short)rr.y);
    r2 = bf2f((unsigned short)rr.z); r3 = bf2f((unsigned short)rr.w);
  } else {
    const float4 rr = ((const float4*)((const float*)Rv + (size_t)row * ND))[tid];
    r0 = rr.x; r1 = rr.y; r2 = rr.z; r3 = rr.w;
  }
  const float x0 = a0.x + a1.x + bd.x + r0;
  const float x1 = a0.y + a1.y + bd.y + r1;
  const float x2 = a0.z + a1.z + bd.z + r2;
  const float x3 = a0.w + a1.w + bd.w + r3;
  float s = x0 + x1 + x2 + x3;
  float sq = x0 * x0 + x1 * x1 + x2 * x2 + x3 * x3;
#pragma unroll
  for (int off = 32; off; off >>= 1) {
    s += __shfl_xor(s, off);
    sq += __shfl_xor(sq, off);
  }
  __shared__ float ss[4], ssq[4];
  const int wave = tid >> 6, lane = tid & 63;
  if (lane == 0) { ss[wave] = s; ssq[wave] = sq; }
  __syncthreads();
  s = ss[0] + ss[1] + ss[2] + ss[3];
  sq = ssq[0] + ssq[1] + ssq[2] + ssq[3];
  const float mu = s * (1.f / (float)ND);
  const float var = sq * (1.f / (float)ND) - mu * mu;
  const float rstd = rsqrtf(var + 1e-5f);
  const float4 gg = ((const float4*)g)[tid];
  const float4 bb = ((const float4*)be)[tid];
  const float o0 = (x0 - mu) * rstd * gg.x + bb.x;
  const float o1 = (x1 - mu) * rstd * gg.y + bb.y;
  const float o2 = (x2 - mu) * rstd * gg.z + bb.z;
  const float o3 = (x3 - mu) * rstd * gg.w + bb.w;
  if (OUTBF16) {
    short4 ov = { f2bf(o0), f2bf(o1), f2bf(o2), f2bf(o3) };
    *(short4*)((short*)out + (size_t)row * ND + tid * 4) = ov;
  } else {
    float4 ov = { o0, o1, o2, o3 };
    ((float4*)((float*)out + (size_t)row * ND))[tid] = ov;
  }
}

extern "C" void kernel_launch(void* const* d_in, const int* in_sizes, int n_in,
                              void* d_out, int out_size, void* d_ws, size_t ws_size,
                              hipStream_t stream) {
  const float* x   = (const float*)d_in[0];
  const int*   pos = (const int*)d_in[1];
  const float* wq  = (const float*)d_in[2];
  const float* bq  = (const float*)d_in[3];
  const float* wk  = (const float*)d_in[4];
  const float* bk  = (const float*)d_in[5];
  const float* wv  = (const float*)d_in[6];
  const float* bv  = (const float*)d_in[7];
  const float* wo  = (const float*)d_in[8];
  const float* bo  = (const float*)d_in[9];
  const float* phb = (const float*)d_in[10];
  const float* w1  = (const float*)d_in[11];
  const float* b1  = (const float*)d_in[12];
  const float* w2  = (const float*)d_in[13];
  const float* b2  = (const float*)d_in[14];
  const float* g1  = (const float*)d_in[15];
  const float* be1 = (const float*)d_in[16];
  const float* g2  = (const float*)d_in[17];
  const float* be2 = (const float*)d_in[18];

  char* ws = (char*)d_ws;
  const size_t MB = 1024 * 1024;
  if (ws_size < 112 * MB) return;
  short* qb     = (short*)(ws + 0 * MB);    // 8MB
  short* kb     = (short*)(ws + 8 * MB);    // 8MB
  short* vb     = (short*)(ws + 16 * MB);   // 8MB
  short* qp     = (short*)(ws + 24 * MB);   // 16MB
  short* kp     = (short*)(ws + 40 * MB);   // 16MB
  short* vt     = (short*)(ws + 56 * MB);   // 8MB
  short* xb     = (short*)(ws + 64 * MB);   // 8MB
  short* attnb  = (short*)(ws + 72 * MB);   // 8MB
  float* attnC0 = (float*)(ws + 0 * MB);    // 16MB (over qb+kb, dead after pope)
  float* attnC1 = (float*)(ws + 24 * MB);   // 16MB (over qp, dead after attn)
  short* hb     = (short*)(ws + 16 * MB);   // 8MB (over vb, dead after pope_pv)
  short* ffh    = (short*)(ws + 40 * MB);   // 32MB (over kp+vt+xb, dead)
  float* ffC0   = (float*)(ws + 72 * MB);   // 16MB (over attnb, dead after wo)
  float* ffC1   = (float*)(ws + 0 * MB);    // 16MB (over attnC0, dead after ln1)
  short* wqT    = (short*)(ws + 88 * MB);
  short* wkT    = (short*)(ws + 90 * MB);
  short* wvT    = (short*)(ws + 92 * MB);
  short* woT    = (short*)(ws + 94 * MB);
  short* w1T    = (short*)(ws + 96 * MB);   // 8MB [DFF][D]
  short* w2T    = (short*)(ws + 104 * MB);  // 8MB [D][DFF]

  dim3 blk(256);
  // weight transposes + x->bf16, one dispatch
  k_prep<<<dim3(5120), blk, 0, stream>>>(wq, wk, wv, wo, w1, w2, x,
                                         wqT, wkT, wvT, woT, w1T, w2T, xb);
  // QKV: 128x256 tiles, merged launch
  k_gemm3<<<dim3(ND / 256, (NB * NS) / 128, 3), blk, 0, stream>>>(
      xb, wqT, wkT, wvT, bq, bk, bv, qb, kb, vb);
  // PoPE + V transpose, one dispatch
  k_pope_pv<<<dim3(3072), blk, 0, stream>>>(qb, kb, vb, pos, phb, qp, kp, vt);
  // attention: 512 blocks, 2/CU, XCD-grouped heads (r11-proven)
  k_attn3<<<dim3(16, NB * NH), dim3(512), 0, stream>>>(qp, kp, vt, attnb);
  // wo: split-K z=2, partials summed in ln1
  k_gemm_sk<<<dim3(ND / 256, (NB * NS) / 128, 2), blk, 0, stream>>>(
      attnb, woT, attnC0, attnC1, NB * NS, ND, ND);
  k_ln3<0, 1><<<dim3(NB * NS), blk, 0, stream>>>(attnC0, attnC1, bo, x, g1, be1, hb);
  // ffn1: full-K, 128x256 tiles
  k_gemm<1, 1><<<dim3(NDFF / 256, (NB * NS) / 128), blk, 0, stream>>>(
      hb, w1T, b1, ffh, NB * NS, NDFF, ND);
  // ffn2: split-K z=2, partials + b2 summed in ln2
  k_gemm_sk<<<dim3(ND / 256, (NB * NS) / 128, 2), blk, 0, stream>>>(
      ffh, w2T, ffC0, ffC1, NB * NS, ND, NDFF);
  k_ln3<1, 0><<<dim3(NB * NS), blk, 0, stream>>>(ffC0, ffC1, b2, hb, g2, be2, (float*)d_out);
}

// Round 16
// 265.655 us; speedup vs baseline: 1.1982x; 1.1982x over previous
//
#include <hip/hip_runtime.h>
#include <hip/hip_bf16.h>
#include <math.h>

#define NB 2
#define NS 2048
#define ND 1024
#define NH 16
#define NHD 64
#define NDFF 4096

typedef __attribute__((ext_vector_type(4))) float f32x4;
typedef __attribute__((ext_vector_type(8))) short bf16x8;

__device__ __forceinline__ short f2bf(float f) {
  union { float f; unsigned u; } v; v.f = f;
  unsigned r = v.u + 0x7fffu + ((v.u >> 16) & 1u);
  return (short)(r >> 16);
}
__device__ __forceinline__ float bf2f(unsigned short u) {
  union { unsigned u; float f; } v; v.u = ((unsigned)u) << 16; return v.f;
}
__device__ __forceinline__ float softplus_f(float x) {
  return fmaxf(x, 0.f) + log1pf(__expf(-fabsf(x)));
}
// async global->LDS, 16B per lane; LDS dest wave-uniform (HW adds lane*16)
__device__ __forceinline__ void gl16(const short* g, short* l) {
  __builtin_amdgcn_global_load_lds(
      (const __attribute__((address_space(1))) void*)g,
      (__attribute__((address_space(3))) void*)l, 16, 0, 0);
}
// XCD-chunked bijective block remap (T1): each XCD owns a contiguous row-slab.
__device__ __forceinline__ void xcd_map(int& row0, int& col0) {
  const int gx = gridDim.x, gy = gridDim.y;
  const int bid = blockIdx.y * gx + blockIdx.x;
  const int rows_px = gy >> 3;
  const int xcd = bid & 7, l = bid >> 3;
  row0 = (xcd * rows_px + (l % rows_px)) * 128;
  col0 = (l / rows_px) * 128;
}

// ============ prep: all 6 weight transposes + x->bf16 in ONE dispatch ============
// [0,1024): wq/wk/wv/wo; [1024,2048): w1; [2048,3072): w2; [3072,5120): xb.
__global__ __launch_bounds__(256) void k_prep(
    const float* __restrict__ wq, const float* __restrict__ wk,
    const float* __restrict__ wv, const float* __restrict__ wo,
    const float* __restrict__ w1, const float* __restrict__ w2,
    const float* __restrict__ x,
    short* __restrict__ wqT, short* __restrict__ wkT, short* __restrict__ wvT,
    short* __restrict__ woT, short* __restrict__ w1T, short* __restrict__ w2T,
    short* __restrict__ xb) {
  __shared__ float t[64][65];
  const int bid = blockIdx.x;
  if (bid >= 3072) {
    const int i = (bid - 3072) * 256 + threadIdx.x;
    const float4 a = ((const float4*)x)[i * 2];
    const float4 b = ((const float4*)x)[i * 2 + 1];
    short tmp[8] = { f2bf(a.x), f2bf(a.y), f2bf(a.z), f2bf(a.w),
                     f2bf(b.x), f2bf(b.y), f2bf(b.z), f2bf(b.w) };
    *(int4*)&xb[(size_t)i * 8] = *(const int4*)tmp;
    return;
  }
  const float* W; short* Wt; int K, N, local;
  if (bid < 1024) {
    const int wsel = bid >> 8; local = bid & 255;
    W  = wsel == 0 ? wq  : wsel == 1 ? wk  : wsel == 2 ? wv  : wo;
    Wt = wsel == 0 ? wqT : wsel == 1 ? wkT : wsel == 2 ? wvT : woT;
    K = ND; N = ND;
  } else if (bid < 2048) {
    local = bid - 1024; W = w1; Wt = w1T; K = ND; N = NDFF;
  } else {
    local = bid - 2048; W = w2; Wt = w2T; K = NDFF; N = ND;
  }
  const int nx = N >> 6;
  const int n0 = (local % nx) * 64, k0 = (local / nx) * 64;
  for (int i = threadIdx.x; i < 4096; i += 256) {
    const int r = i >> 6, c = i & 63;
    t[r][c] = W[(size_t)(k0 + r) * N + n0 + c];
  }
  __syncthreads();
  for (int i = threadIdx.x; i < 4096; i += 256) {
    const int r = i >> 6, c = i & 63;
    Wt[(size_t)(n0 + r) * K + k0 + c] = f2bf(t[c][r]);
  }
}

// ============ PoPE + V-transpose in ONE dispatch ============
// [0,2048): pope elementwise (q side pre-scaled by 1/sqrt(128)*log2e so the
// attention softmax is a single v_exp_f32); [2048,3072): prep_v tiles.
__global__ __launch_bounds__(256) void k_pope_pv(const short* __restrict__ qb,
    const short* __restrict__ kb, const short* __restrict__ vb,
    const int* __restrict__ positions, const float* __restrict__ phb,
    short* __restrict__ qp, short* __restrict__ kp, short* __restrict__ vt) {
  __shared__ short t[64][72];
  const int bid = blockIdx.x;
  if (bid < 2048) {
    const size_t i8 = ((size_t)bid * 256 + threadIdx.x) * 8;
    const int d0 = (int)(i8 & 63);
    const int h  = (int)((i8 >> 6) & 15);
    const int s  = (int)((i8 >> 10) & 2047);
    const int b  = (int)(i8 >> 21);
    const float posf = (float)positions[s];
    const float QSC = 0.12751743305610407f;  // 1/sqrt(128) * log2(e)
    int4 qv = *(const int4*)&qb[i8];
    int4 kv = *(const int4*)&kb[i8];
    const short* qs = (const short*)&qv;
    const short* ks = (const short*)&kv;
    short qc[8], qsn[8], kc[8], ksn[8];
#pragma unroll
    for (int j = 0; j < 8; j++) {
      const int d = d0 + j;
      const float freq = __expf(-(float)d * (float)(9.210340371976184 / 64.0));
      const float muq = softplus_f(bf2f((unsigned short)qs[j])) * QSC;
      const float muk = softplus_f(bf2f((unsigned short)ks[j]));
      float cb = phb[h * 64 + d];
      cb = fminf(fmaxf(cb, -6.283185307179586f), 0.f);
      float snq, csq, snk, csk;
      __sincosf(posf * freq, &snq, &csq);
      __sincosf(posf * freq + cb, &snk, &csk);
      qc[j] = f2bf(muq * csq); qsn[j] = f2bf(muq * snq);
      kc[j] = f2bf(muk * csk); ksn[j] = f2bf(muk * snk);
    }
    const size_t o = (((size_t)(b * 16 + h) * NS + s) * 128) + d0;
    *(int4*)&qp[o] = *(const int4*)qc;
    *(int4*)&qp[o + 64] = *(const int4*)qsn;
    *(int4*)&kp[o] = *(const int4*)kc;
    *(int4*)&kp[o + 64] = *(const int4*)ksn;
  } else {
    const int local = bid - 2048;
    const int bh = local >> 5, b = bh >> 4, h = bh & 15;
    const int s0 = (local & 31) * 64;
    for (int i = threadIdx.x; i < 512; i += 256) {
      const int sl = i >> 3, d8 = (i & 7) * 8;
      int4 vv = *(const int4*)&vb[((size_t)(b * NS + s0 + sl) * NH + h) * NHD + d8];
      const short* sp = (const short*)&vv;
#pragma unroll
      for (int j = 0; j < 8; j++) t[d8 + j][sl] = sp[j];
    }
    __syncthreads();
    for (int i = threadIdx.x; i < 512; i += 256) {
      const int d = i >> 3, c8 = (i & 7) * 8;
      *(int4*)&vt[((size_t)bh * 64 + d) * NS + s0 + c8] = *(const int4*)&t[d][c8];
    }
  }
}

// ==== GEMM core: 2-phase double-buffered, global_load_lds, prefetch-first ====
#define BKK 32

__device__ __forceinline__ void gemm_core(const short* __restrict__ A,
    const short* __restrict__ Wt, const int K, const int kbeg, const int kend,
    const int row0, const int col0, short* lsA, short* lsB, f32x4 acc[4][4]) {
  const int tid = threadIdx.x;
  const int lane = tid & 63, wave = tid >> 6;
  const int lr = lane & 15, lk8 = (lane >> 4) << 3;
  const int wr = wave >> 1, wc = wave & 1;
  const int srow = lane >> 2, scol = (lane & 3) << 3;
  const int wbase = wave * 32;
#pragma unroll
  for (int m = 0; m < 4; m++)
#pragma unroll
    for (int n = 0; n < 4; n++) acc[m][n] = 0.f;
  const short* gA0 = &A[(size_t)(row0 + wbase + srow) * K + scol];
  const short* gA1 = gA0 + (size_t)16 * K;
  const short* gB0 = &Wt[(size_t)(col0 + wbase + srow) * K + scol];
  const short* gB1 = gB0 + (size_t)16 * K;
  short* const lA0 = lsA + wbase * 32;
  short* const lB0 = lsB + wbase * 32;
  auto stage = [&](int buf, int kk) {
    const int o = buf * 4096;
    gl16(gA0 + kk, lA0 + o);
    gl16(gA1 + kk, lA0 + o + 512);
    gl16(gB0 + kk, lB0 + o);
    gl16(gB1 + kk, lB0 + o + 512);
  };
  stage(0, kbeg);
  __syncthreads();
  int cur = 0;
  for (int k0 = kbeg; k0 < kend; k0 += BKK) {
    if (k0 + BKK < kend) stage(cur ^ 1, k0 + BKK);  // issue-early: overlaps compute
    const short* la = lsA + cur * 4096;
    const short* lb = lsB + cur * 4096;
    bf16x8 af[4], bf_[4];
#pragma unroll
    for (int m = 0; m < 4; m++)
      af[m] = *(const bf16x8*)&la[(wr * 64 + m * 16 + lr) * 32 + lk8];
#pragma unroll
    for (int n = 0; n < 4; n++)
      bf_[n] = *(const bf16x8*)&lb[(wc * 64 + n * 16 + lr) * 32 + lk8];
#pragma unroll
    for (int m = 0; m < 4; m++)
#pragma unroll
      for (int n = 0; n < 4; n++)
        acc[m][n] = __builtin_amdgcn_mfma_f32_16x16x32_bf16(af[m], bf_[n], acc[m][n], 0, 0, 0);
    __syncthreads();  // drains this iter's prefetch (vmcnt) + read-done (lgkm)
    cur ^= 1;
  }
}

template<int RELU, int OUTBF16>
__global__ __launch_bounds__(256) void k_gemm(const short* __restrict__ A,
    const short* __restrict__ Wt, const float* __restrict__ bias,
    void* __restrict__ C, int M, int N, int K) {
  __shared__ short lsA[2 * 4096], lsB[2 * 4096];
  f32x4 acc[4][4];
  int row0, col0;
  xcd_map(row0, col0);
  gemm_core(A, Wt, K, 0, K, row0, col0, lsA, lsB, acc);
  const int lane = threadIdx.x & 63, wave = threadIdx.x >> 6;
  const int lr = lane & 15, r4 = (lane >> 4) << 2;
  const int wr = wave >> 1, wc = wave & 1;
#pragma unroll
  for (int m = 0; m < 4; m++) {
#pragma unroll
    for (int n = 0; n < 4; n++) {
      const int col = col0 + wc * 64 + n * 16 + lr;
      const float bv = bias[col];
#pragma unroll
      for (int r = 0; r < 4; r++) {
        const int row = row0 + wr * 64 + m * 16 + r4 + r;
        float val = acc[m][n][r] + bv;
        if (RELU) val = fmaxf(val, 0.f);
        if (OUTBF16) ((short*)C)[(size_t)row * N + col] = f2bf(val);
        else ((float*)C)[(size_t)row * N + col] = val;
      }
    }
  }
}

// QKV merged: grid.z picks weight/bias/output. bf16 out.
__global__ __launch_bounds__(256) void k_gemm3(const short* __restrict__ xb,
    const short* __restrict__ wqT, const short* __restrict__ wkT,
    const short* __restrict__ wvT, const float* __restrict__ bq,
    const float* __restrict__ bk, const float* __restrict__ bv,
    short* __restrict__ qb, short* __restrict__ kb, short* __restrict__ vb) {
  __shared__ short lsA[2 * 4096], lsB[2 * 4096];
  const int z = blockIdx.z;
  const short* Wt = (z == 0) ? wqT : (z == 1) ? wkT : wvT;
  const float* bias = (z == 0) ? bq : (z == 1) ? bk : bv;
  short* C = (z == 0) ? qb : (z == 1) ? kb : vb;
  f32x4 acc[4][4];
  int row0, col0;
  xcd_map(row0, col0);
  gemm_core(xb, Wt, ND, 0, ND, row0, col0, lsA, lsB, acc);
  const int lane = threadIdx.x & 63, wave = threadIdx.x >> 6;
  const int lr = lane & 15, r4 = (lane >> 4) << 2;
  const int wr = wave >> 1, wc = wave & 1;
#pragma unroll
  for (int m = 0; m < 4; m++) {
#pragma unroll
    for (int n = 0; n < 4; n++) {
      const int col = col0 + wc * 64 + n * 16 + lr;
      const float bvs = bias[col];
#pragma unroll
      for (int r = 0; r < 4; r++) {
        const int row = row0 + wr * 64 + m * 16 + r4 + r;
        C[(size_t)row * ND + col] = f2bf(acc[m][n][r] + bvs);
      }
    }
  }
}

// Split-K GEMM: grid.z=2 halves of K; writes unbiased f32 partials to C0/C1.
__global__ __launch_bounds__(256) void k_gemm_sk(const short* __restrict__ A,
    const short* __restrict__ Wt, float* __restrict__ C0, float* __restrict__ C1,
    int M, int N, int K) {
  __shared__ short lsA[2 * 4096], lsB[2 * 4096];
  f32x4 acc[4][4];
  const int z = blockIdx.z;
  const int khalf = K >> 1, kbeg = z * khalf, kend = kbeg + khalf;
  int row0, col0;
  xcd_map(row0, col0);
  gemm_core(A, Wt, K, kbeg, kend, row0, col0, lsA, lsB, acc);
  float* C = z ? C1 : C0;
  const int lane = threadIdx.x & 63, wave = threadIdx.x >> 6;
  const int lr = lane & 15, r4 = (lane >> 4) << 2;
  const int wr = wave >> 1, wc = wave & 1;
#pragma unroll
  for (int m = 0; m < 4; m++) {
#pragma unroll
    for (int n = 0; n < 4; n++) {
      const int col = col0 + wc * 64 + n * 16 + lr;
#pragma unroll
      for (int r = 0; r < 4; r++) {
        const int row = row0 + wr * 64 + m * 16 + r4 + r;
        C[(size_t)row * N + col] = acc[m][n][r];
      }
    }
  }
}

// ============ Attention (causal, softmax1), MFMA flash ============
// m=0 fixed (softmax1 is shift-invariant; scores provably < ~6, no overflow).
// q_p carries scale*log2e -> p = v_exp_f32(s) directly. P truncated to bf16
// (<=0.8% rel err); lsum accumulates the SAME truncated value (consistent).
__device__ __forceinline__ void attn_proc(const bf16x8 aq[4], f32x4 acc_o[4],
    float l_p[4], const int rowb, const int kb,
    const short (*kpl)[136], const short (*vl)[72], short (*pl)[72],
    const int lr, const int lk) {
  f32x4 s_acc[4];
#pragma unroll
  for (int n = 0; n < 4; n++) s_acc[n] = 0.f;
#pragma unroll
  for (int ks = 0; ks < 4; ks++) {
    bf16x8 bk_[4];
#pragma unroll
    for (int n = 0; n < 4; n++)
      bk_[n] = *(const bf16x8*)&kpl[n * 16 + lr][ks * 32 + lk * 8];
#pragma unroll
    for (int n = 0; n < 4; n++)
      s_acc[n] = __builtin_amdgcn_mfma_f32_16x16x32_bf16(aq[ks], bk_[n], s_acc[n], 0, 0, 0);
  }
  const bool domask = (kb + 63 > rowb);  // wave-uniform: diagonal-crossing chunk
#pragma unroll
  for (int n = 0; n < 4; n++) {
#pragma unroll
    for (int r = 0; r < 4; r++) {
      float p = __builtin_amdgcn_exp2f(s_acc[n][r]);  // raw v_exp_f32
      if (domask) {
        const int rel = rowb + lk * 4 + r - kb;
        p = (n * 16 + lr <= rel) ? p : 0.f;
      }
      unsigned pu = __float_as_uint(p) & 0xFFFF0000u;  // truncate to bf16
      l_p[r] += __uint_as_float(pu);
      pl[lk * 4 + r][n * 16 + lr] = (short)(pu >> 16);
    }
  }
#pragma unroll
  for (int ks = 0; ks < 2; ks++) {
    const bf16x8 ap = *(const bf16x8*)&pl[lr][ks * 32 + lk * 8];
    bf16x8 bv_[4];
#pragma unroll
    for (int nd = 0; nd < 4; nd++)
      bv_[nd] = *(const bf16x8*)&vl[nd * 16 + lr][ks * 32 + lk * 8];
#pragma unroll
    for (int nd = 0; nd < 4; nd++)
      acc_o[nd] = __builtin_amdgcn_mfma_f32_16x16x32_bf16(ap, bv_[nd], acc_o[nd], 0, 0, 0);
  }
}

// grid (16, 32), 512 threads, 2 blocks/CU. XCD-grouped remap: each XCD owns
// 4 whole (b,h) heads so one head's K/V panel lives in ONE L2.
// Block: waves 0-3 own 64-row tile tH=31-bx, waves 4-7 own tile bx.
__global__ __launch_bounds__(512) void k_attn3(
    const short* __restrict__ qp, const short* __restrict__ kp,
    const short* __restrict__ vt, short* __restrict__ attn) {
  __shared__ short kp_l[2][64][136];
  __shared__ short v_l[2][64][72];
  __shared__ short p_l[8][16][72];
  const int bid = blockIdx.y * gridDim.x + blockIdx.x;
  const int xcd = bid & 7, o = bid >> 3;
  const int bh = xcd * 4 + (o >> 4);
  const int bx = o & 15;
  const int b = bh >> 4, h = bh & 15;
  const int tid = threadIdx.x, wave = tid >> 6, lane = tid & 63;
  const int lr = lane & 15, lk = lane >> 4;
  const int tHeavy = 31 - bx;
  const int myTile = (wave < 4) ? tHeavy : bx;
  const int rowb = myTile * 64 + (wave & 3) * 16;
  const int nch = tHeavy + 1;

  bf16x8 aq[4];
  {
    const short* qrow = qp + ((size_t)bh * NS + rowb + lr) * 128;
#pragma unroll
    for (int ks = 0; ks < 4; ks++)
      aq[ks] = *(const bf16x8*)&qrow[ks * 32 + lk * 8];
  }
  f32x4 acc[4];
  float lsum[4];
#pragma unroll
  for (int r = 0; r < 4; r++) lsum[r] = 0.f;
#pragma unroll
  for (int n = 0; n < 4; n++) acc[n] = 0.f;

  const short* kpb = kp + (size_t)bh * NS * 128;
  const short* vtb = vt + (size_t)bh * 64 * NS;
  const int krow = tid >> 3, kcol = (tid & 7) * 16;
  const int vrow = tid >> 3, vcol = (tid & 7) * 8;

  int4 rk0, rk1, rv;
  {
    const short* s = &kpb[(size_t)krow * 128 + kcol];
    rk0 = ((const int4*)s)[0]; rk1 = ((const int4*)s)[1];
    rv = *(const int4*)&vtb[(size_t)vrow * NS + vcol];
  }
  ((int4*)&kp_l[0][krow][kcol])[0] = rk0;
  ((int4*)&kp_l[0][krow][kcol])[1] = rk1;
  *(int4*)&v_l[0][vrow][vcol] = rv;
  __syncthreads();

  for (int c = 0; c < nch; c++) {
    const int kb = c * 64;
    const int cur = c & 1;
    const bool more = (c + 1) < nch;
    if (more) {
      const int kb2 = kb + 64;
      const short* s = &kpb[(size_t)(kb2 + krow) * 128 + kcol];
      rk0 = ((const int4*)s)[0]; rk1 = ((const int4*)s)[1];
      rv = *(const int4*)&vtb[(size_t)vrow * NS + kb2 + vcol];
    }
    if (rowb + 15 >= kb)
      attn_proc(aq, acc, lsum, rowb, kb, kp_l[cur], v_l[cur], p_l[wave], lr, lk);
    if (more) {
      // writes target buffer cur^1 (nobody reads it this iteration); the single
      // barrier below both publishes these writes and closes the read phase.
      ((int4*)&kp_l[cur ^ 1][krow][kcol])[0] = rk0;
      ((int4*)&kp_l[cur ^ 1][krow][kcol])[1] = rk1;
      *(int4*)&v_l[cur ^ 1][vrow][vcol] = rv;
    }
    __syncthreads();
  }
  // epilogue: single cross-lane reduce of the deferred row sums (lane bits 0-3)
#pragma unroll
  for (int r = 0; r < 4; r++) {
    float s = lsum[r];
#pragma unroll
    for (int off = 8; off; off >>= 1) s += __shfl_xor(s, off);
    lsum[r] = 1.f / (1.f + s);   // softmax1 with m=0: denom = 1 + sum
  }
#pragma unroll
  for (int nd = 0; nd < 4; nd++) {
#pragma unroll
    for (int r = 0; r < 4; r++) {
      const int d = nd * 16 + lr;
      const int row = rowb + lk * 4 + r;
      attn[(((size_t)b * NS + row) * NH + h) * NHD + d] = f2bf(acc[nd][r] * lsum[r]);
    }
  }
}

// ==== LayerNorm with fused partial-sum + bias: x = A0 + A1 + badd + R ====
template<int RBF16, int OUTBF16>
__global__ __launch_bounds__(256) void k_ln3(const float* __restrict__ A0,
    const float* __restrict__ A1, const float* __restrict__ badd,
    const void* __restrict__ Rv, const float* __restrict__ g,
    const float* __restrict__ be, void* __restrict__ out) {
  const int row = blockIdx.x, tid = threadIdx.x;
  const float4 a0 = ((const float4*)(A0 + (size_t)row * ND))[tid];
  const float4 a1 = ((const float4*)(A1 + (size_t)row * ND))[tid];
  const float4 bd = ((const float4*)badd)[tid];
  float r0, r1, r2, r3;
  if (RBF16) {
    short4 rr = *(const short4*)((const short*)Rv + (size_t)row * ND + tid * 4);
    r0 = bf2f((unsigned short)rr.x); r1 = bf2f((unsigned short)rr.y);
    r2 = bf2f((unsigned short)rr.z); r3 = bf2f((unsigned short)rr.w);
  } else {
    const float4 rr = ((const float4*)((const float*)Rv + (size_t)row * ND))[tid];
    r0 = rr.x; r1 = rr.y; r2 = rr.z; r3 = rr.w;
  }
  const float x0 = a0.x + a1.x + bd.x + r0;
  const float x1 = a0.y + a1.y + bd.y + r1;
  const float x2 = a0.z + a1.z + bd.z + r2;
  const float x3 = a0.w + a1.w + bd.w + r3;
  float s = x0 + x1 + x2 + x3;
  float sq = x0 * x0 + x1 * x1 + x2 * x2 + x3 * x3;
#pragma unroll
  for (int off = 32; off; off >>= 1) {
    s += __shfl_xor(s, off);
    sq += __shfl_xor(sq, off);
  }
  __shared__ float ss[4], ssq[4];
  const int wave = tid >> 6, lane = tid & 63;
  if (lane == 0) { ss[wave] = s; ssq[wave] = sq; }
  __syncthreads();
  s = ss[0] + ss[1] + ss[2] + ss[3];
  sq = ssq[0] + ssq[1] + ssq[2] + ssq[3];
  const float mu = s * (1.f / (float)ND);
  const float var = sq * (1.f / (float)ND) - mu * mu;
  const float rstd = rsqrtf(var + 1e-5f);
  const float4 gg = ((const float4*)g)[tid];
  const float4 bb = ((const float4*)be)[tid];
  const float o0 = (x0 - mu) * rstd * gg.x + bb.x;
  const float o1 = (x1 - mu) * rstd * gg.y + bb.y;
  const float o2 = (x2 - mu) * rstd * gg.z + bb.z;
  const float o3 = (x3 - mu) * rstd * gg.w + bb.w;
  if (OUTBF16) {
    short4 ov = { f2bf(o0), f2bf(o1), f2bf(o2), f2bf(o3) };
    *(short4*)((short*)out + (size_t)row * ND + tid * 4) = ov;
  } else {
    float4 ov = { o0, o1, o2, o3 };
    ((float4*)((float*)out + (size_t)row * ND))[tid] = ov;
  }
}

extern "C" void kernel_launch(void* const* d_in, const int* in_sizes, int n_in,
                              void* d_out, int out_size, void* d_ws, size_t ws_size,
                              hipStream_t stream) {
  const float* x   = (const float*)d_in[0];
  const int*   pos = (const int*)d_in[1];
  const float* wq  = (const float*)d_in[2];
  const float* bq  = (const float*)d_in[3];
  const float* wk  = (const float*)d_in[4];
  const float* bk  = (const float*)d_in[5];
  const float* wv  = (const float*)d_in[6];
  const float* bv  = (const float*)d_in[7];
  const float* wo  = (const float*)d_in[8];
  const float* bo  = (const float*)d_in[9];
  const float* phb = (const float*)d_in[10];
  const float* w1  = (const float*)d_in[11];
  const float* b1  = (const float*)d_in[12];
  const float* w2  = (const float*)d_in[13];
  const float* b2  = (const float*)d_in[14];
  const float* g1  = (const float*)d_in[15];
  const float* be1 = (const float*)d_in[16];
  const float* g2  = (const float*)d_in[17];
  const float* be2 = (const float*)d_in[18];

  char* ws = (char*)d_ws;
  const size_t MB = 1024 * 1024;
  if (ws_size < 112 * MB) return;
  short* qb     = (short*)(ws + 0 * MB);    // 8MB
  short* kb     = (short*)(ws + 8 * MB);    // 8MB
  short* vb     = (short*)(ws + 16 * MB);   // 8MB
  short* qp     = (short*)(ws + 24 * MB);   // 16MB
  short* kp     = (short*)(ws + 40 * MB);   // 16MB
  short* vt     = (short*)(ws + 56 * MB);   // 8MB
  short* xb     = (short*)(ws + 64 * MB);   // 8MB
  short* attnb  = (short*)(ws + 72 * MB);   // 8MB
  float* attnC0 = (float*)(ws + 0 * MB);    // 16MB (over qb+kb, dead after pope)
  float* attnC1 = (float*)(ws + 24 * MB);   // 16MB (over qp, dead after attn)
  short* hb     = (short*)(ws + 16 * MB);   // 8MB (over vb, dead after pope_pv)
  short* ffh    = (short*)(ws + 40 * MB);   // 32MB (over kp+vt+xb, dead)
  float* ffC0   = (float*)(ws + 72 * MB);   // 16MB (over attnb, dead after wo)
  float* ffC1   = (float*)(ws + 0 * MB);    // 16MB (over attnC0, dead after ln1)
  short* wqT    = (short*)(ws + 88 * MB);
  short* wkT    = (short*)(ws + 90 * MB);
  short* wvT    = (short*)(ws + 92 * MB);
  short* woT    = (short*)(ws + 94 * MB);
  short* w1T    = (short*)(ws + 96 * MB);   // 8MB [DFF][D]
  short* w2T    = (short*)(ws + 104 * MB);  // 8MB [D][DFF]

  dim3 blk(256);
  // weight transposes + x->bf16, one dispatch
  k_prep<<<dim3(5120), blk, 0, stream>>>(wq, wk, wv, wo, w1, w2, x,
                                         wqT, wkT, wvT, woT, w1T, w2T, xb);
  // QKV: one merged launch, 768 blocks co-resident
  k_gemm3<<<dim3(ND / 128, (NB * NS) / 128, 3), blk, 0, stream>>>(
      xb, wqT, wkT, wvT, bq, bk, bv, qb, kb, vb);
  // PoPE + V transpose, one dispatch
  k_pope_pv<<<dim3(3072), blk, 0, stream>>>(qb, kb, vb, pos, phb, qp, kp, vt);
  // attention: 512 blocks, 2/CU, XCD-grouped heads
  k_attn3<<<dim3(16, NB * NH), dim3(512), 0, stream>>>(qp, kp, vt, attnb);
  // wo: split-K z=2, partials summed in ln1
  k_gemm_sk<<<dim3(ND / 128, (NB * NS) / 128, 2), blk, 0, stream>>>(
      attnb, woT, attnC0, attnC1, NB * NS, ND, ND);
  k_ln3<0, 1><<<dim3(NB * NS), blk, 0, stream>>>(attnC0, attnC1, bo, x, g1, be1, hb);
  // ffn1: full-K (1024 blocks, 4/CU)
  k_gemm<1, 1><<<dim3(NDFF / 128, (NB * NS) / 128), blk, 0, stream>>>(
      hb, w1T, b1, ffh, NB * NS, NDFF, ND);
  // ffn2: split-K z=2, partials + b2 summed in ln2
  k_gemm_sk<<<dim3(ND / 128, (NB * NS) / 128, 2), blk, 0, stream>>>(
      ffh, w2T, ffC0, ffC1, NB * NS, ND, NDFF);
  k_ln3<1, 0><<<dim3(NB * NS), blk, 0, stream>>>(ffC0, ffC1, b2, hb, g2, be2, (float*)d_out);
}